// Round 1
// baseline (178.399 us; speedup 1.0000x reference)
//
#include <hip/hip_runtime.h>

// TrajectoryScore: truncated-exponential mixture scoring + segment sums.
// 64 segments x 100,000 obs. Memory-bound stream: 153.6 MB read -> ~24 us floor.

constexpr int ELT_BATCH     = 64;
constexpr int OBS_PER_ELT   = 100000;
constexpr int GROUPS_PER_SEG = OBS_PER_ELT / 4;      // 4 obs per thread-iter (12 floats = 3 float4)
constexpr int F4_PER_SEG     = OBS_PER_ELT * 3 / 4;  // 75000 float4 per segment
constexpr int BLOCKS_PER_SEG = 32;
constexpr int BLOCK          = 256;

__device__ __forceinline__ float wave_reduce_sum(float v) {
    #pragma unroll
    for (int off = 32; off > 0; off >>= 1)
        v += __shfl_down(v, off, 64);
    return v;
}

__global__ __launch_bounds__(BLOCK) void TrajectoryScore_58145267253396_kernel(
    const float4* __restrict__ pred4,
    const float4* __restrict__ obs4,
    const float*  __restrict__ h_arr,
    const float*  __restrict__ lam_arr,
    const float*  __restrict__ th_arr,
    float*        __restrict__ out)
{
    const int seg        = blockIdx.x / BLOCKS_PER_SEG;
    const int blk_in_seg = blockIdx.x % BLOCKS_PER_SEG;
    const int tid        = threadIdx.x;

    // Wave-uniform per-segment params (broadcast scalar loads).
    const float h      = h_arr[seg];
    const float lam    = lam_arr[seg];
    const float th     = th_arr[seg];
    const float inv_th = 1.0f / th;
    const float coef   = h * lam / (1.0f - __expf(-lam));  // h * lam / (1 - e^-lam)
    const float omh    = 1.0f - h;
    const float nli    = -lam * inv_th;                    // exp(nli * s2) = exp(-lam * v)

    float ll = 0.0f;   // sum of log(p) over close obs
    float hs = 0.0f;   // sum of p_hit_post over close & real-hit obs

    const int seg_base = seg * F4_PER_SEG;

    for (int g = blk_in_seg * BLOCK + tid; g < GROUPS_PER_SEG; g += BLOCKS_PER_SEG * BLOCK) {
        const int base = seg_base + g * 3;
        const float4 a0 = pred4[base], a1 = pred4[base + 1], a2 = pred4[base + 2];
        const float4 b0 = obs4[base],  b1 = obs4[base + 1],  b2 = obs4[base + 2];

        float dx, dy, dz, s2[4];
        dx = a0.x - b0.x; dy = a0.y - b0.y; dz = a0.z - b0.z;
        s2[0] = dx * dx + dy * dy + dz * dz;
        dx = a0.w - b0.w; dy = a1.x - b1.x; dz = a1.y - b1.y;
        s2[1] = dx * dx + dy * dy + dz * dz;
        dx = a1.z - b1.z; dy = a1.w - b1.w; dz = a2.x - b2.x;
        s2[2] = dx * dx + dy * dy + dz * dz;
        dx = a2.y - b2.y; dy = a2.z - b2.z; dz = a2.w - b2.w;
        s2[3] = dx * dx + dy * dy + dz * dz;

        #pragma unroll
        for (int k = 0; k < 4; ++k) {
            const float s     = s2[k];
            const float e     = __expf(nli * s);     // exp(-lam * s2/th)
            const float p_hit = coef * e;
            const float p     = p_hit + omh;
            const bool  close = s < th;
            const float lp    = __logf(p);
            ll += close ? lp : 0.0f;
            const float post  = p_hit / p;
            hs += (close && post > 0.95f) ? post : 0.0f;
        }
    }

    // Block reduction: 64-lane shuffle, then LDS across the 4 waves.
    ll = wave_reduce_sum(ll);
    hs = wave_reduce_sum(hs);

    __shared__ float sll[BLOCK / 64];
    __shared__ float shs[BLOCK / 64];
    const int wave = tid >> 6;
    const int lane = tid & 63;
    if (lane == 0) { sll[wave] = ll; shs[wave] = hs; }
    __syncthreads();
    if (tid == 0) {
        float L = 0.0f, H = 0.0f;
        #pragma unroll
        for (int w = 0; w < BLOCK / 64; ++w) { L += sll[w]; H += shs[w]; }
        atomicAdd(&out[seg], L);
        atomicAdd(&out[ELT_BATCH + seg], H);
        atomicAdd(&out[2 * ELT_BATCH + seg], H);  // hits_raw == hits
    }
}

extern "C" void kernel_launch(void* const* d_in, const int* in_sizes, int n_in,
                              void* d_out, int out_size, void* d_ws, size_t ws_size,
                              hipStream_t stream) {
    const float4* pred4  = (const float4*)d_in[0];
    const float4* obs4   = (const float4*)d_in[1];
    const float*  h_arr  = (const float*)d_in[2];
    const float*  lam_arr = (const float*)d_in[3];
    const float*  th_arr = (const float*)d_in[4];
    float* out = (float*)d_out;

    // Harness poisons d_out to 0xAA before timed replays — zero it ourselves.
    hipMemsetAsync(out, 0, out_size * sizeof(float), stream);

    dim3 grid(ELT_BATCH * BLOCKS_PER_SEG);
    dim3 block(BLOCK);
    TrajectoryScore_58145267253396_kernel<<<grid, block, 0, stream>>>(
        pred4, obs4, h_arr, lam_arr, th_arr, out);
}